// Round 11
// baseline (363.418 us; speedup 1.0000x reference)
//
#include <hip/hip_runtime.h>
#include <hip/hip_bf16.h>
#include <cstdint>

#define I_ 16
#define T_ 64
#define Q_ 197
#define K_ 30
#define H_ 8
#define D_ 64
#define E_ 512

typedef float f32x2 __attribute__((ext_vector_type(2)));
typedef float f32x4 __attribute__((ext_vector_type(4)));
typedef short bf16x8 __attribute__((ext_vector_type(8)));

static constexpr float INV_SQRT_E = 0.044194173824159216f;  // 1/sqrt(512)
static constexpr float C197 = 1.0f / 197.0f;
static constexpr int   QK = Q_ * K_;   // 5910

// workspace offsets (in float units)
#define OFF_QBF   0          // bf16 [I,Q,H,D]
#define OFF_KBF   806912     // bf16 [T,K,H,D]
#define OFF_V     1298432    // f32  [T,K,H,D]
#define OFF_TV    2281472    // f32  [I,Q,H,D]
#define OFF_ASUM  3895296    // f32  [I,T,H,K]
#define OFF_TASUM 4141056    // f32  [I,T,H,Q]
#define OFF_PBF   5754880    // bf16 [2048][512]  (rows 0..1023 i2t, 1024.. t2i)
#define OFF_WBF   6279168    // bf16 [1024][512]  (rows 0..511 W_out, 512.. W_out_text)

__device__ inline short f2bs(float x) { __hip_bfloat16 h = __float2bfloat16(x); return *reinterpret_cast<short*>(&h); }
__device__ inline float bs2f(short s) { __hip_bfloat16 h = *reinterpret_cast<__hip_bfloat16*>(&s); return __bfloat162float(h); }

// ---------------- K1: projections; q,k -> bf16, v,tv -> f32; W -> bf16 ----------------
__global__ __launch_bounds__(512) void proj_kernel(
    const float* __restrict__ image, const float* __restrict__ text,
    const float* __restrict__ Wq, const float* __restrict__ Wk,
    const float* __restrict__ Wv, const float* __restrict__ Wtv,
    const float* __restrict__ W_out, const float* __restrict__ W_out_text,
    float* __restrict__ ws)
{
  const int NQ4 = (I_ * Q_) / 4;   // 788
  const int NT4 = (T_ * K_) / 4;   // 480
  int bb = blockIdx.x;
  int tid = threadIdx.x;

  if (bb >= NQ4 + 2 * NT4 + NQ4) {           // mode 4: W fp32 -> bf16, 4 rows/block
    int row0 = (bb - (NQ4 + 2 * NT4 + NQ4)) * 4;   // 0..1020
    __hip_bfloat16* Wb = (__hip_bfloat16*)(ws + OFF_WBF);
    const float* src = (row0 < 512) ? (W_out + row0 * E_) : (W_out_text + (row0 - 512) * E_);
    #pragma unroll
    for (int rr = 0; rr < 4; ++rr)
      Wb[(size_t)(row0 + rr) * E_ + tid] = __float2bfloat16(src[rr * E_ + tid]);
    return;
  }

  const float* X; const float* W; int row0; int mode;
  if (bb < NQ4)             { X = image; W = Wq;  row0 = bb * 4;               mode = 0; }
  else if (bb < NQ4 + NT4)  { X = text;  W = Wk;  row0 = (bb - NQ4) * 4;       mode = 1; }
  else if (bb < NQ4 + 2*NT4){ X = text;  W = Wv;  row0 = (bb - NQ4 - NT4) * 4; mode = 2; }
  else                      { X = image; W = Wtv; row0 = (bb - NQ4 - 2*NT4)*4; mode = 3; }

  __shared__ float s_x[4][E_];        // 8 KB
  __shared__ float s_w[D_][D_ + 1];   // 16.6 KB, +1 pad
  for (int idx = tid; idx < D_ * D_; idx += 512) s_w[idx >> 6][idx & 63] = W[idx];
  #pragma unroll
  for (int rr = 0; rr < 4; ++rr) s_x[rr][tid] = X[(size_t)(row0 + rr) * E_ + tid];
  __syncthreads();

  int h = tid >> 6, dout = tid & 63;
  float a0 = 0.f, a1 = 0.f, a2 = 0.f, a3 = 0.f;
  #pragma unroll
  for (int d = 0; d < D_; ++d) {
    float w = s_w[dout][d];
    a0 = fmaf(s_x[0][h * 64 + d], w, a0);
    a1 = fmaf(s_x[1][h * 64 + d], w, a1);
    a2 = fmaf(s_x[2][h * 64 + d], w, a2);
    a3 = fmaf(s_x[3][h * 64 + d], w, a3);
  }
  if (mode <= 1) {
    __hip_bfloat16* Y = (__hip_bfloat16*)(ws + (mode == 0 ? OFF_QBF : OFF_KBF));
    Y[(size_t)(row0 + 0) * E_ + tid] = __float2bfloat16(a0);
    Y[(size_t)(row0 + 1) * E_ + tid] = __float2bfloat16(a1);
    Y[(size_t)(row0 + 2) * E_ + tid] = __float2bfloat16(a2);
    Y[(size_t)(row0 + 3) * E_ + tid] = __float2bfloat16(a3);
  } else {
    float* Y = ws + (mode == 2 ? OFF_V : OFF_TV);
    Y[(size_t)(row0 + 0) * E_ + tid] = a0;
    Y[(size_t)(row0 + 1) * E_ + tid] = a1;
    Y[(size_t)(row0 + 2) * E_ + tid] = a2;
    Y[(size_t)(row0 + 3) * E_ + tid] = a3;
  }
}

// ---------------- K2: swapped-operand MFMA attention, register-direct epilogue ----------------
// S^T = mfma(K-frag, Q-frag): lane holds q = lane&15 (one row), k = (lane>>4)*4 + reg.
// Per lane, per q-tile: 8 k-columns as two 4-elem chunks {4lg..4lg+3} and {16+4lg..} (k<30).
__global__ __launch_bounds__(256, 4) void attn_kernel(
    const __hip_bfloat16* __restrict__ qbf, const __hip_bfloat16* __restrict__ kbf,
    const int* __restrict__ text_mask,
    float* __restrict__ attn_out, float* __restrict__ tattn_out,
    float* __restrict__ A_sum, float* __restrict__ TA_sum)
{
  int b = blockIdx.x;                  // b = ((i*T)+t)*H + h
  int h = b & 7, t = (b >> 3) & 63, i = b >> 9;
  int tid = threadIdx.x;
  int w = tid >> 6, lane = tid & 63;
  int lr = lane & 15, lg = lane >> 4;

  __shared__ float s_cd[4][32];
  __shared__ float s_ca[4][32];
  __shared__ float s_invd[32];

  // per-lane masks for its 8 k-columns (k=0 is cls: always 1; k>=30 invalid: 0)
  int mA[4], mB[4];
  #pragma unroll
  for (int r = 0; r < 4; ++r) {
    int kA = 4 * lg + r;
    mA[r] = (kA == 0) ? 1 : text_mask[t * (K_ - 1) + kA - 1];
    int kB = 16 + 4 * lg + r;
    mB[r] = (kB < K_) ? text_mask[t * (K_ - 1) + kB - 1] : 0;
  }

  const __hip_bfloat16* qb = qbf + ((size_t)(i * Q_) * H_ + h) * D_;  // row stride 512
  const __hip_bfloat16* kb = kbf + ((size_t)(t * K_) * H_ + h) * D_;

  // K fragments (A operand): rows lr and 16+lr, k-dim halves
  const bf16x8* bp0 = (const bf16x8*)(kb + (size_t)lr * (H_ * D_) + lg * 8);
  const bf16x8* bp1 = (const bf16x8*)(kb + (size_t)(16 + lr) * (H_ * D_) + lg * 8);
  bf16x8 kf00 = bp0[0], kf01 = bp0[4];
  bf16x8 kf10 = bp1[0], kf11 = bp1[4];

  float cdA[4] = {}, cdB[4] = {}, caA[4] = {}, caB[4] = {};
  bf16x8 epk[4];                       // packed e per owned q-tile (static-indexed)

  float* abase = attn_out + (size_t)b * QK;

  #pragma unroll
  for (int j = 0; j < 4; ++j) {
    int qt = w + 4 * j;
    epk[j] = bf16x8{0, 0, 0, 0, 0, 0, 0, 0};
    if (qt < 13) {
      int qrow = qt * 16 + lr;
      const bf16x8* qp = (const bf16x8*)(qb + (size_t)qrow * (H_ * D_) + lg * 8);
      bf16x8 q0 = qp[0], q1 = qp[4];
      f32x4 acc0 = {0.f, 0.f, 0.f, 0.f}, acc1 = {0.f, 0.f, 0.f, 0.f};
      acc0 = __builtin_amdgcn_mfma_f32_16x16x32_bf16(kf00, q0, acc0, 0, 0, 0);
      acc0 = __builtin_amdgcn_mfma_f32_16x16x32_bf16(kf01, q1, acc0, 0, 0, 0);
      acc1 = __builtin_amdgcn_mfma_f32_16x16x32_bf16(kf10, q0, acc1, 0, 0, 0);
      acc1 = __builtin_amdgcn_mfma_f32_16x16x32_bf16(kf11, q1, acc1, 0, 0, 0);
      bool vr = qrow < Q_;
      float eA[4], eB[4];
      #pragma unroll
      for (int r = 0; r < 4; ++r) {
        eA[r] = (vr && mA[r]) ? __expf(acc0[r] * INV_SQRT_E) : 0.f;
        eB[r] = (vr && mB[r]) ? __expf(acc1[r] * INV_SQRT_E) : 0.f;
      }
      float rs = ((eA[0] + eA[1]) + (eA[2] + eA[3])) + ((eB[0] + eB[1]) + (eB[2] + eB[3]));
      rs += __shfl_xor(rs, 16);
      rs += __shfl_xor(rs, 32);
      float ivr = (vr && rs > 0.f) ? (1.0f / rs) : 0.f;
      #pragma unroll
      for (int r = 0; r < 4; ++r) {
        cdA[r] += eA[r]; caA[r] += eA[r] * ivr;
        cdB[r] += eB[r]; caB[r] += eB[r] * ivr;
      }
      if (vr) {
        float* arow = abase + qrow * K_;
        f32x2 s0 = { eA[0] * ivr, eA[1] * ivr };
        f32x2 s1 = { eA[2] * ivr, eA[3] * ivr };
        __builtin_nontemporal_store(s0, (f32x2*)(arow + 4 * lg));
        __builtin_nontemporal_store(s1, (f32x2*)(arow + 4 * lg + 2));
        f32x2 s2 = { eB[0] * ivr, eB[1] * ivr };
        __builtin_nontemporal_store(s2, (f32x2*)(arow + 16 + 4 * lg));
        if (lg < 3) {
          f32x2 s3 = { eB[2] * ivr, eB[3] * ivr };
          __builtin_nontemporal_store(s3, (f32x2*)(arow + 16 + 4 * lg + 2));
        }
      }
      epk[j] = bf16x8{ f2bs(eA[0]), f2bs(eA[1]), f2bs(eA[2]), f2bs(eA[3]),
                       f2bs(eB[0]), f2bs(eB[1]), f2bs(eB[2]), f2bs(eB[3]) };
    }
  }

  // column reduce across the 16 lr lanes (each lane's 8 k-slots)
  #pragma unroll
  for (int r = 0; r < 4; ++r) {
    cdA[r] += __shfl_xor(cdA[r], 1); cdA[r] += __shfl_xor(cdA[r], 2);
    cdA[r] += __shfl_xor(cdA[r], 4); cdA[r] += __shfl_xor(cdA[r], 8);
    cdB[r] += __shfl_xor(cdB[r], 1); cdB[r] += __shfl_xor(cdB[r], 2);
    cdB[r] += __shfl_xor(cdB[r], 4); cdB[r] += __shfl_xor(cdB[r], 8);
    caA[r] += __shfl_xor(caA[r], 1); caA[r] += __shfl_xor(caA[r], 2);
    caA[r] += __shfl_xor(caA[r], 4); caA[r] += __shfl_xor(caA[r], 8);
    caB[r] += __shfl_xor(caB[r], 1); caB[r] += __shfl_xor(caB[r], 2);
    caB[r] += __shfl_xor(caB[r], 4); caB[r] += __shfl_xor(caB[r], 8);
  }
  if (lr == 0) {
    #pragma unroll
    for (int r = 0; r < 4; ++r) {
      s_cd[w][4 * lg + r] = cdA[r];
      s_ca[w][4 * lg + r] = caA[r];
      s_cd[w][16 + 4 * lg + r] = cdB[r];
      s_ca[w][16 + 4 * lg + r] = caB[r];
    }
  }
  __syncthreads();

  if (tid < 32) {
    float dsum = (s_cd[0][tid] + s_cd[1][tid]) + (s_cd[2][tid] + s_cd[3][tid]);
    float pa   = (s_ca[0][tid] + s_ca[1][tid]) + (s_ca[2][tid] + s_ca[3][tid]);
    int mc = (tid == 0) ? 1 : (tid < K_ ? text_mask[t * (K_ - 1) + tid - 1] : 0);
    s_invd[tid] = (mc && dsum > 0.f) ? (1.0f / dsum) : 0.f;
    if (tid < K_) A_sum[(size_t)b * K_ + tid] = pa;
  }
  __syncthreads();

  float idA[4], idB[4];
  #pragma unroll
  for (int r = 0; r < 4; ++r) { idA[r] = s_invd[4 * lg + r]; idB[r] = s_invd[16 + 4 * lg + r]; }

  float* tbase = tattn_out + (size_t)b * QK;
  #pragma unroll
  for (int j = 0; j < 4; ++j) {
    int qt = w + 4 * j;
    if (qt < 13) {
      int qrow = qt * 16 + lr;
      bool vr = qrow < Q_;
      float tvA[4], tvB[4];
      #pragma unroll
      for (int r = 0; r < 4; ++r) {
        float e = bs2f(epk[j][r]);
        tvA[r] = mA[r] ? e * idA[r] : C197;
      }
      #pragma unroll
      for (int r = 0; r < 4; ++r) {
        float e = bs2f(epk[j][4 + r]);
        int kB = 16 + 4 * lg + r;
        tvB[r] = (kB < K_) ? (mB[r] ? e * idB[r] : C197) : 0.f;
      }
      float ta = ((tvA[0] + tvA[1]) + (tvA[2] + tvA[3])) + ((tvB[0] + tvB[1]) + (tvB[2] + tvB[3]));
      ta += __shfl_xor(ta, 16);
      ta += __shfl_xor(ta, 32);
      if (vr) {
        float* trow = tbase + qrow * K_;
        f32x2 s0 = { tvA[0], tvA[1] };
        f32x2 s1 = { tvA[2], tvA[3] };
        __builtin_nontemporal_store(s0, (f32x2*)(trow + 4 * lg));
        __builtin_nontemporal_store(s1, (f32x2*)(trow + 4 * lg + 2));
        f32x2 s2 = { tvB[0], tvB[1] };
        __builtin_nontemporal_store(s2, (f32x2*)(trow + 16 + 4 * lg));
        if (lg < 3) {
          f32x2 s3 = { tvB[2], tvB[3] };
          __builtin_nontemporal_store(s3, (f32x2*)(trow + 16 + 4 * lg + 2));
        }
        if (lg == 0) TA_sum[(size_t)b * Q_ + qrow] = ta;
      }
    }
  }
}

// ---------------- K3: fused pooled i2t + t2i -> Pbf (bf16) ----------------
__global__ __launch_bounds__(512) void pool_fused_kernel(
    const float* __restrict__ A_sum, const float* __restrict__ TA_sum,
    const float* __restrict__ ws_v, const float* __restrict__ ws_tv,
    __hip_bfloat16* __restrict__ Pbf)
{
  int bt = blockIdx.x;           // i*T + t
  int t = bt & 63;
  int i = bt >> 6;
  int tid = threadIdx.x;
  int h = tid >> 6, d = tid & 63;
  __shared__ float s_A[H_ * K_];     // 240
  __shared__ float s_TA[H_ * Q_];    // 1576
  if (tid < H_ * K_) s_A[tid] = A_sum[(size_t)bt * H_ * K_ + tid];
  for (int idx = tid; idx < H_ * Q_; idx += 512) s_TA[idx] = TA_sum[(size_t)bt * H_ * Q_ + idx];
  __syncthreads();

  // i2t pooled: 30-term dot
  {
    float a0 = 0.f, a1 = 0.f;
    #pragma unroll
    for (int kk = 0; kk < K_; kk += 2) {
      a0 = fmaf(s_A[h * K_ + kk],     ws_v[((size_t)(t * K_ + kk)     * H_ + h) * D_ + d], a0);
      a1 = fmaf(s_A[h * K_ + kk + 1], ws_v[((size_t)(t * K_ + kk + 1) * H_ + h) * D_ + d], a1);
    }
    Pbf[(size_t)bt * E_ + tid] = __float2bfloat16((a0 + a1) * C197);
  }

  // t2i pooled: 197-term dot
  {
    float a0 = 0.f, a1 = 0.f, a2 = 0.f, a3 = 0.f;
    int qq = 0;
    for (; qq + 4 <= Q_; qq += 4) {
      a0 = fmaf(s_TA[h * Q_ + qq + 0], ws_tv[((size_t)(i * Q_ + qq + 0) * H_ + h) * D_ + d], a0);
      a1 = fmaf(s_TA[h * Q_ + qq + 1], ws_tv[((size_t)(i * Q_ + qq + 1) * H_ + h) * D_ + d], a1);
      a2 = fmaf(s_TA[h * Q_ + qq + 2], ws_tv[((size_t)(i * Q_ + qq + 2) * H_ + h) * D_ + d], a2);
      a3 = fmaf(s_TA[h * Q_ + qq + 3], ws_tv[((size_t)(i * Q_ + qq + 3) * H_ + h) * D_ + d], a3);
    }
    for (; qq < Q_; ++qq)
      a0 = fmaf(s_TA[h * Q_ + qq], ws_tv[((size_t)(i * Q_ + qq) * H_ + h) * D_ + d], a0);
    Pbf[(size_t)(1024 + bt) * E_ + tid] = __float2bfloat16(((a0 + a1) + (a2 + a3)) * (1.0f / 30.0f));
  }
}

// ---------------- K4: MFMA out-projection: out[m,n] = P[m,:] . W[n,:] + bias ----------------
__global__ __launch_bounds__(256) void outproj_mfma_kernel(
    const __hip_bfloat16* __restrict__ Pbf, const __hip_bfloat16* __restrict__ Wbf,
    const float* __restrict__ b_out, const float* __restrict__ b_out_text,
    float* __restrict__ out)
{
  int mt = blockIdx.x;             // 0..127
  int z = (mt >= 64);              // text half
  int tid = threadIdx.x;
  int w = tid >> 6, lane = tid & 63;
  int lr = lane & 15, lg = lane >> 4;

  const __hip_bfloat16* A = Pbf + (size_t)(mt * 16 + lr) * E_ + lg * 8;
  const __hip_bfloat16* B = Wbf + (size_t)(z * 512) * E_;
  f32x4 acc[8] = {};
  for (int ks = 0; ks < 16; ++ks) {
    bf16x8 a = *(const bf16x8*)(A + ks * 32);
    #pragma unroll
    for (int nt = 0; nt < 8; ++nt) {
      int n0 = w * 128 + nt * 16;
      bf16x8 bv = *(const bf16x8*)(B + (size_t)(n0 + lr) * E_ + ks * 32 + lg * 8);
      acc[nt] = __builtin_amdgcn_mfma_f32_16x16x32_bf16(a, bv, acc[nt], 0, 0, 0);
    }
  }
  const float* bias = z ? b_out_text : b_out;
  int row0 = mt * 16 + lg * 4;
  #pragma unroll
  for (int nt = 0; nt < 8; ++nt) {
    int n = w * 128 + nt * 16 + lr;
    float bv = bias[n];
    #pragma unroll
    for (int r = 0; r < 4; ++r)
      out[(size_t)(row0 + r) * E_ + n] = acc[nt][r] + bv;
  }
}

extern "C" void kernel_launch(void* const* d_in, const int* in_sizes, int n_in,
                              void* d_out, int out_size, void* d_ws, size_t ws_size,
                              hipStream_t stream)
{
  const float* image      = (const float*)d_in[0];
  const float* text       = (const float*)d_in[1];
  const int*   tmask      = (const int*)d_in[2];
  const float* Wq         = (const float*)d_in[3];
  const float* Wk         = (const float*)d_in[4];
  const float* Wv         = (const float*)d_in[5];
  const float* W_out      = (const float*)d_in[6];
  const float* b_out      = (const float*)d_in[7];
  const float* Wtv        = (const float*)d_in[8];
  const float* W_out_text = (const float*)d_in[9];
  const float* b_out_text = (const float*)d_in[10];

  float* out = (float*)d_out;
  float* ws  = (float*)d_ws;

  const __hip_bfloat16* qbf = (const __hip_bfloat16*)(ws + OFF_QBF);
  const __hip_bfloat16* kbf = (const __hip_bfloat16*)(ws + OFF_KBF);
  float* v     = ws + OFF_V;
  float* tv    = ws + OFF_TV;
  float* Asum  = ws + OFF_ASUM;
  float* TAsum = ws + OFF_TASUM;
  __hip_bfloat16* Pbf = (__hip_bfloat16*)(ws + OFF_PBF);
  __hip_bfloat16* Wbf = (__hip_bfloat16*)(ws + OFF_WBF);

  float* attn    = out + (size_t)2 * I_ * T_ * E_;        // [I,T,H,Q,K]
  float* tattn   = attn + (size_t)I_ * T_ * H_ * Q_ * K_; // [I,T,H,Q,K]

  const int NQ4 = (I_ * Q_) / 4, NT4 = (T_ * K_) / 4;
  proj_kernel<<<NQ4 + 2 * NT4 + NQ4 + 256, 512, 0, stream>>>(
      image, text, Wq, Wk, Wv, Wtv, W_out, W_out_text, ws);
  attn_kernel<<<I_ * T_ * H_, 256, 0, stream>>>(qbf, kbf, tmask, attn, tattn, Asum, TAsum);
  pool_fused_kernel<<<I_ * T_, 512, 0, stream>>>(Asum, TAsum, v, tv, Pbf);
  outproj_mfma_kernel<<<128, 256, 0, stream>>>(Pbf, Wbf, b_out, b_out_text, out);
}

// Round 12
// 191.614 us; speedup vs baseline: 1.8966x; 1.8966x over previous
//
#include <hip/hip_runtime.h>
#include <hip/hip_bf16.h>
#include <cstdint>

#define I_ 16
#define T_ 64
#define Q_ 197
#define K_ 30
#define H_ 8
#define D_ 64
#define E_ 512

typedef float f32x2 __attribute__((ext_vector_type(2)));
typedef float f32x4 __attribute__((ext_vector_type(4)));
typedef short bf16x8 __attribute__((ext_vector_type(8)));

static constexpr float INV_SQRT_E = 0.044194173824159216f;  // 1/sqrt(512)
static constexpr float C197 = 1.0f / 197.0f;
static constexpr int   QK = Q_ * K_;   // 5910

// workspace offsets (in float units)
#define OFF_QBF   0          // bf16 [I,Q,H,D]  1,613,824 elems
#define OFF_KBF   806912     // bf16 [T,K,H,D]    983,040 elems
#define OFF_VBF   1298432    // bf16 [T,K,H,D]    983,040 elems
#define OFF_TVBF  1789952    // bf16 [I,Q,H,D]  1,613,824 elems
#define OFF_ASUM  2596864    // f32  [I,T,H,K]
#define OFF_TASUM 2842624    // f32  [I,T,H,Q]
#define OFF_PBF   4456448    // bf16 [2048][512]  (rows 0..1023 i2t, 1024.. t2i)
#define OFF_WBF   4980736    // bf16 [1024][512]  (rows 0..511 W_out, 512.. W_out_text)

// ---------------- K1: projections; q,k,v,tv -> bf16; W -> bf16 ----------------
__global__ __launch_bounds__(512) void proj_kernel(
    const float* __restrict__ image, const float* __restrict__ text,
    const float* __restrict__ Wq, const float* __restrict__ Wk,
    const float* __restrict__ Wv, const float* __restrict__ Wtv,
    const float* __restrict__ W_out, const float* __restrict__ W_out_text,
    float* __restrict__ ws)
{
  const int NQ4 = (I_ * Q_) / 4;   // 788
  const int NT4 = (T_ * K_) / 4;   // 480
  int bb = blockIdx.x;
  int tid = threadIdx.x;

  if (bb >= NQ4 + 2 * NT4 + NQ4) {           // mode 4: W fp32 -> bf16, 4 rows/block
    int row0 = (bb - (NQ4 + 2 * NT4 + NQ4)) * 4;   // 0..1020
    __hip_bfloat16* Wb = (__hip_bfloat16*)(ws + OFF_WBF);
    const float* src = (row0 < 512) ? (W_out + row0 * E_) : (W_out_text + (row0 - 512) * E_);
    #pragma unroll
    for (int rr = 0; rr < 4; ++rr)
      Wb[(size_t)(row0 + rr) * E_ + tid] = __float2bfloat16(src[rr * E_ + tid]);
    return;
  }

  const float* X; const float* W; int row0; int mode;
  if (bb < NQ4)             { X = image; W = Wq;  row0 = bb * 4;               mode = 0; }
  else if (bb < NQ4 + NT4)  { X = text;  W = Wk;  row0 = (bb - NQ4) * 4;       mode = 1; }
  else if (bb < NQ4 + 2*NT4){ X = text;  W = Wv;  row0 = (bb - NQ4 - NT4) * 4; mode = 2; }
  else                      { X = image; W = Wtv; row0 = (bb - NQ4 - 2*NT4)*4; mode = 3; }

  __shared__ float s_x[4][E_];        // 8 KB
  __shared__ float s_w[D_][D_ + 1];   // 16.6 KB, +1 pad
  for (int idx = tid; idx < D_ * D_; idx += 512) s_w[idx >> 6][idx & 63] = W[idx];
  #pragma unroll
  for (int rr = 0; rr < 4; ++rr) s_x[rr][tid] = X[(size_t)(row0 + rr) * E_ + tid];
  __syncthreads();

  int h = tid >> 6, dout = tid & 63;
  float a0 = 0.f, a1 = 0.f, a2 = 0.f, a3 = 0.f;
  #pragma unroll
  for (int d = 0; d < D_; ++d) {
    float w = s_w[dout][d];
    a0 = fmaf(s_x[0][h * 64 + d], w, a0);
    a1 = fmaf(s_x[1][h * 64 + d], w, a1);
    a2 = fmaf(s_x[2][h * 64 + d], w, a2);
    a3 = fmaf(s_x[3][h * 64 + d], w, a3);
  }
  static const int offs[4] = { OFF_QBF, OFF_KBF, OFF_VBF, OFF_TVBF };
  __hip_bfloat16* Y = (__hip_bfloat16*)(ws + offs[mode]);
  Y[(size_t)(row0 + 0) * E_ + tid] = __float2bfloat16(a0);
  Y[(size_t)(row0 + 1) * E_ + tid] = __float2bfloat16(a1);
  Y[(size_t)(row0 + 2) * E_ + tid] = __float2bfloat16(a2);
  Y[(size_t)(row0 + 3) * E_ + tid] = __float2bfloat16(a3);
}

// ---------------- K2: register MFMA attention + bf16 LDS e-tile + flat f4 epilogue ----------------
// (round-9 proven structure, byte-identical)
__global__ __launch_bounds__(256, 8) void attn_kernel(
    const __hip_bfloat16* __restrict__ qbf, const __hip_bfloat16* __restrict__ kbf,
    const int* __restrict__ text_mask,
    float* __restrict__ attn_out, float* __restrict__ tattn_out,
    float* __restrict__ A_sum, float* __restrict__ TA_sum)
{
  int b = blockIdx.x;                  // b = ((i*T)+t)*H + h
  int h = b & 7, t = (b >> 3) & 63, i = b >> 9;
  int tid = threadIdx.x;
  int w = tid >> 6, lane = tid & 63;
  int lr = lane & 15, lg = lane >> 4;

  __shared__ __hip_bfloat16 s_e[208 * 30];   // 12,480 B raw exp tile (bf16; masked = 0)
  __shared__ float s_invrow[208];
  __shared__ float s_cd[4][32];
  __shared__ float s_ca[4][32];
  __shared__ float s_invd[32];
  __shared__ int   s_mask[32];

  if (tid < 32) s_mask[tid] = (tid == 0) ? 1 : (tid < K_ ? text_mask[t * (K_ - 1) + tid - 1] : 0);

  int m0 = (lr == 0) ? 1 : text_mask[t * (K_ - 1) + lr - 1];
  int m1 = (lr < 14) ? text_mask[t * (K_ - 1) + 15 + lr] : 0;

  const __hip_bfloat16* qb = qbf + ((size_t)(i * Q_) * H_ + h) * D_;  // row stride 512
  const __hip_bfloat16* kb = kbf + ((size_t)(t * K_) * H_ + h) * D_;

  const bf16x8* bp0 = (const bf16x8*)(kb + (size_t)lr * (H_ * D_) + lg * 8);
  const bf16x8* bp1 = (const bf16x8*)(kb + (size_t)(16 + lr) * (H_ * D_) + lg * 8);
  bf16x8 b00 = bp0[0], b01 = bp0[4];
  bf16x8 b10 = bp1[0], b11 = bp1[4];

  float cd0 = 0.f, cd1 = 0.f, ca0 = 0.f, ca1 = 0.f;

  #pragma unroll
  for (int j = 0; j < 4; ++j) {
    int mt = w + 4 * j;
    if (mt < 13) {
      const bf16x8* ap = (const bf16x8*)(qb + (size_t)(mt * 16 + lr) * (H_ * D_) + lg * 8);
      bf16x8 a0 = ap[0], a1 = ap[4];
      f32x4 acc0 = {0.f, 0.f, 0.f, 0.f}, acc1 = {0.f, 0.f, 0.f, 0.f};
      acc0 = __builtin_amdgcn_mfma_f32_16x16x32_bf16(a0, b00, acc0, 0, 0, 0);
      acc0 = __builtin_amdgcn_mfma_f32_16x16x32_bf16(a1, b01, acc0, 0, 0, 0);
      acc1 = __builtin_amdgcn_mfma_f32_16x16x32_bf16(a0, b10, acc1, 0, 0, 0);
      acc1 = __builtin_amdgcn_mfma_f32_16x16x32_bf16(a1, b11, acc1, 0, 0, 0);
      int row0 = mt * 16 + lg * 4;
      float v0[4], v1[4];
      #pragma unroll
      for (int r = 0; r < 4; ++r) {
        bool vr = (row0 + r) < Q_;
        v0[r] = (vr && m0) ? __expf(acc0[r] * INV_SQRT_E) : 0.f;
        v1[r] = (vr && m1) ? __expf(acc1[r] * INV_SQRT_E) : 0.f;
        s_e[(row0 + r) * K_ + lr] = __float2bfloat16(v0[r]);
        if (lr < 14) s_e[(row0 + r) * K_ + 16 + lr] = __float2bfloat16(v1[r]);
      }
      #pragma unroll
      for (int r = 0; r < 4; ++r) {
        float s = v0[r] + v1[r];
        s += __shfl_xor(s, 1);
        s += __shfl_xor(s, 2);
        s += __shfl_xor(s, 4);
        s += __shfl_xor(s, 8);
        float iv = ((row0 + r) < Q_ && s > 0.f) ? (1.0f / s) : 0.f;
        if (lr == 0) s_invrow[row0 + r] = iv;
        cd0 += v0[r]; ca0 += v0[r] * iv;
        cd1 += v1[r]; ca1 += v1[r] * iv;
      }
    }
  }

  cd0 += __shfl_xor(cd0, 16); cd0 += __shfl_xor(cd0, 32);
  ca0 += __shfl_xor(ca0, 16); ca0 += __shfl_xor(ca0, 32);
  cd1 += __shfl_xor(cd1, 16); cd1 += __shfl_xor(cd1, 32);
  ca1 += __shfl_xor(ca1, 16); ca1 += __shfl_xor(ca1, 32);
  if (lane < 16) {
    s_cd[w][lr] = cd0; s_cd[w][lr + 16] = cd1;
    s_ca[w][lr] = ca0; s_ca[w][lr + 16] = ca1;
  }
  __syncthreads();

  if (tid < 32) {
    int col = tid;
    float d  = s_cd[0][col] + s_cd[1][col] + s_cd[2][col] + s_cd[3][col];
    float pa = s_ca[0][col] + s_ca[1][col] + s_ca[2][col] + s_ca[3][col];
    s_invd[col] = (s_mask[col] && d > 0.f) ? (1.0f / d) : 0.f;
    if (col < K_) A_sum[(size_t)b * K_ + col] = pa;
  }
  __syncthreads();

  // TA_sum per row (masked col contributes exactly 1/197)
  if (tid < Q_) {
    float ta = 0.f;
    #pragma unroll
    for (int kk = 0; kk < K_; ++kk) {
      float ev = __bfloat162float(s_e[tid * K_ + kk]);
      ta += s_mask[kk] ? ev * s_invd[kk] : C197;
    }
    TA_sum[(size_t)b * Q_ + tid] = ta;
  }

  // ---- flat float4 non-temporal copy-out of both tiles ----
  {
    float* abase = attn_out  + (size_t)b * QK;
    float* tbase = tattn_out + (size_t)b * QK;
    int head = (b & 1) ? 2 : 0;
    if (tid == 0) {
      int e0 = head ? 0 : (QK - 2);
      float ex = __bfloat162float(s_e[e0]);
      float ey = __bfloat162float(s_e[e0 + 1]);
      int r0 = e0 / K_, c0 = e0 - r0 * K_;
      int r1 = (e0 + 1) / K_, c1 = (e0 + 1) - r1 * K_;
      f32x2 av = { ex * s_invrow[r0], ey * s_invrow[r1] };
      f32x2 tv2 = { s_mask[c0] ? ex * s_invd[c0] : C197,
                    s_mask[c1] ? ey * s_invd[c1] : C197 };
      __builtin_nontemporal_store(av,  (f32x2*)(abase + e0));
      __builtin_nontemporal_store(tv2, (f32x2*)(tbase + e0));
    }
    for (int fi = tid; fi < 1477; fi += 256) {
      int base = head + fi * 4;
      float ev[4]; int rw[4]; int cl[4];
      #pragma unroll
      for (int e = 0; e < 4; ++e) {
        int idx = base + e;
        ev[e] = __bfloat162float(s_e[idx]);
        rw[e] = idx / K_;
        cl[e] = idx - rw[e] * K_;
      }
      f32x4 av, tv4;
      #pragma unroll
      for (int e = 0; e < 4; ++e) {
        av[e]  = ev[e] * s_invrow[rw[e]];
        tv4[e] = s_mask[cl[e]] ? ev[e] * s_invd[cl[e]] : C197;
      }
      __builtin_nontemporal_store(av,  (f32x4*)(abase + base));
      __builtin_nontemporal_store(tv4, (f32x4*)(tbase + base));
    }
  }
}

// ---------------- K3: fused pooled i2t + t2i -> Pbf (bf16; v/tv read as bf16) ----------------
__global__ __launch_bounds__(512) void pool_fused_kernel(
    const float* __restrict__ A_sum, const float* __restrict__ TA_sum,
    const __hip_bfloat16* __restrict__ vbf, const __hip_bfloat16* __restrict__ tvbf,
    __hip_bfloat16* __restrict__ Pbf)
{
  int bt = blockIdx.x;           // i*T + t
  int t = bt & 63;
  int i = bt >> 6;
  int tid = threadIdx.x;
  int h = tid >> 6, d = tid & 63;
  __shared__ float s_A[H_ * K_];     // 240
  __shared__ float s_TA[H_ * Q_];    // 1576
  if (tid < H_ * K_) s_A[tid] = A_sum[(size_t)bt * H_ * K_ + tid];
  for (int idx = tid; idx < H_ * Q_; idx += 512) s_TA[idx] = TA_sum[(size_t)bt * H_ * Q_ + idx];
  __syncthreads();

  // i2t pooled: 30-term dot
  {
    float a0 = 0.f, a1 = 0.f;
    #pragma unroll
    for (int kk = 0; kk < K_; kk += 2) {
      a0 = fmaf(s_A[h * K_ + kk],
                __bfloat162float(vbf[((size_t)(t * K_ + kk)     * H_ + h) * D_ + d]), a0);
      a1 = fmaf(s_A[h * K_ + kk + 1],
                __bfloat162float(vbf[((size_t)(t * K_ + kk + 1) * H_ + h) * D_ + d]), a1);
    }
    Pbf[(size_t)bt * E_ + tid] = __float2bfloat16((a0 + a1) * C197);
  }

  // t2i pooled: 197-term dot
  {
    float a0 = 0.f, a1 = 0.f, a2 = 0.f, a3 = 0.f;
    int qq = 0;
    for (; qq + 4 <= Q_; qq += 4) {
      a0 = fmaf(s_TA[h * Q_ + qq + 0],
                __bfloat162float(tvbf[((size_t)(i * Q_ + qq + 0) * H_ + h) * D_ + d]), a0);
      a1 = fmaf(s_TA[h * Q_ + qq + 1],
                __bfloat162float(tvbf[((size_t)(i * Q_ + qq + 1) * H_ + h) * D_ + d]), a1);
      a2 = fmaf(s_TA[h * Q_ + qq + 2],
                __bfloat162float(tvbf[((size_t)(i * Q_ + qq + 2) * H_ + h) * D_ + d]), a2);
      a3 = fmaf(s_TA[h * Q_ + qq + 3],
                __bfloat162float(tvbf[((size_t)(i * Q_ + qq + 3) * H_ + h) * D_ + d]), a3);
    }
    for (; qq < Q_; ++qq)
      a0 = fmaf(s_TA[h * Q_ + qq],
                __bfloat162float(tvbf[((size_t)(i * Q_ + qq) * H_ + h) * D_ + d]), a0);
    Pbf[(size_t)(1024 + bt) * E_ + tid] = __float2bfloat16(((a0 + a1) + (a2 + a3)) * (1.0f / 30.0f));
  }
}

// ---------------- K4: MFMA out-projection: out[m,n] = P[m,:] . W[n,:] + bias ----------------
__global__ __launch_bounds__(256) void outproj_mfma_kernel(
    const __hip_bfloat16* __restrict__ Pbf, const __hip_bfloat16* __restrict__ Wbf,
    const float* __restrict__ b_out, const float* __restrict__ b_out_text,
    float* __restrict__ out)
{
  int mt = blockIdx.x;             // 0..127
  int z = (mt >= 64);              // text half
  int tid = threadIdx.x;
  int w = tid >> 6, lane = tid & 63;
  int lr = lane & 15, lg = lane >> 4;

  const __hip_bfloat16* A = Pbf + (size_t)(mt * 16 + lr) * E_ + lg * 8;
  const __hip_bfloat16* B = Wbf + (size_t)(z * 512) * E_;
  f32x4 acc[8] = {};
  for (int ks = 0; ks < 16; ++ks) {
    bf16x8 a = *(const bf16x8*)(A + ks * 32);
    #pragma unroll
    for (int nt = 0; nt < 8; ++nt) {
      int n0 = w * 128 + nt * 16;
      bf16x8 bv = *(const bf16x8*)(B + (size_t)(n0 + lr) * E_ + ks * 32 + lg * 8);
      acc[nt] = __builtin_amdgcn_mfma_f32_16x16x32_bf16(a, bv, acc[nt], 0, 0, 0);
    }
  }
  const float* bias = z ? b_out_text : b_out;
  int row0 = mt * 16 + lg * 4;
  #pragma unroll
  for (int nt = 0; nt < 8; ++nt) {
    int n = w * 128 + nt * 16 + lr;
    float bv = bias[n];
    #pragma unroll
    for (int r = 0; r < 4; ++r)
      out[(size_t)(row0 + r) * E_ + n] = acc[nt][r] + bv;
  }
}

extern "C" void kernel_launch(void* const* d_in, const int* in_sizes, int n_in,
                              void* d_out, int out_size, void* d_ws, size_t ws_size,
                              hipStream_t stream)
{
  const float* image      = (const float*)d_in[0];
  const float* text       = (const float*)d_in[1];
  const int*   tmask      = (const int*)d_in[2];
  const float* Wq         = (const float*)d_in[3];
  const float* Wk         = (const float*)d_in[4];
  const float* Wv         = (const float*)d_in[5];
  const float* W_out      = (const float*)d_in[6];
  const float* b_out      = (const float*)d_in[7];
  const float* Wtv        = (const float*)d_in[8];
  const float* W_out_text = (const float*)d_in[9];
  const float* b_out_text = (const float*)d_in[10];

  float* out = (float*)d_out;
  float* ws  = (float*)d_ws;

  const __hip_bfloat16* qbf  = (const __hip_bfloat16*)(ws + OFF_QBF);
  const __hip_bfloat16* kbf  = (const __hip_bfloat16*)(ws + OFF_KBF);
  const __hip_bfloat16* vbf  = (const __hip_bfloat16*)(ws + OFF_VBF);
  const __hip_bfloat16* tvbf = (const __hip_bfloat16*)(ws + OFF_TVBF);
  float* Asum  = ws + OFF_ASUM;
  float* TAsum = ws + OFF_TASUM;
  __hip_bfloat16* Pbf = (__hip_bfloat16*)(ws + OFF_PBF);
  __hip_bfloat16* Wbf = (__hip_bfloat16*)(ws + OFF_WBF);

  float* attn    = out + (size_t)2 * I_ * T_ * E_;        // [I,T,H,Q,K]
  float* tattn   = attn + (size_t)I_ * T_ * H_ * Q_ * K_; // [I,T,H,Q,K]

  const int NQ4 = (I_ * Q_) / 4, NT4 = (T_ * K_) / 4;
  proj_kernel<<<NQ4 + 2 * NT4 + NQ4 + 256, 512, 0, stream>>>(
      image, text, Wq, Wk, Wv, Wtv, W_out, W_out_text, ws);
  attn_kernel<<<I_ * T_ * H_, 256, 0, stream>>>(qbf, kbf, tmask, attn, tattn, Asum, TAsum);
  pool_fused_kernel<<<I_ * T_, 512, 0, stream>>>(Asum, TAsum, vbf, tvbf, Pbf);
  outproj_mfma_kernel<<<128, 256, 0, stream>>>(Pbf, Wbf, b_out, b_out_text, out);
}